// Round 1
// baseline (305.914 us; speedup 1.0000x reference)
//
#include <hip/hip_runtime.h>

// CRF NLL: B=1024, S=512, T=48.
// One wave (64 lanes) per batch element. Lane j holds forward state j (j<48);
// lanes 48..63 clone lane 47 (clamped column) so no per-step masking is needed.
// Forward recursion done in scaled linear domain:
//   p_{s+1}[j] = (sum_k p_s[k] * E[k][j]) * 2^(em[s][j]*log2e),  E = exp(trans)
// with exact power-of-2 rescale every 4 steps (exponent extraction -> integer
// log2 accumulator L). Broadcast of p[k] via v_readlane_b32 (uniform SGPR
// operand feeding v_fma_f32 directly).

#define T 48
#define SLEN 512
#define BATCH 1024

__device__ __forceinline__ float wave_sum(float v) {
    #pragma unroll
    for (int m = 32; m >= 1; m >>= 1) v += __shfl_xor(v, m, 64);
    return v;
}

__device__ __forceinline__ float wave_max(float v) {
    #pragma unroll
    for (int m = 32; m >= 1; m >>= 1) v = fmaxf(v, __shfl_xor(v, m, 64));
    return v;
}

__device__ __forceinline__ float rlane(float v, int k) {
    return __int_as_float(__builtin_amdgcn_readlane(__float_as_int(v), k));
}

__global__ __launch_bounds__(64) void crf_kernel(
    const float* __restrict__ em,      // (B,S,T)
    const int*   __restrict__ tags,    // (B,S)
    const float* __restrict__ mask,    // (B,S)
    const float* __restrict__ trans,   // (T,T)  trans[k*T+j] = k(prev) -> j(cur) in fwd
    const float* __restrict__ start_t, // (T,)
    const float* __restrict__ end_t,   // (T,)
    float*       __restrict__ out)     // scalar
{
    constexpr float LOG2E = 1.4426950408889634f;
    constexpr float LN2   = 0.6931471805599453f;

    const int b    = blockIdx.x;
    const int lane = threadIdx.x;
    const int j    = lane < T ? lane : (T - 1);   // clamp: lanes 48..63 clone col 47

    const float* em_b   = em   + (size_t)b * SLEN * T;
    const float* mask_b = mask + (size_t)b * SLEN;
    const int*   tags_b = tags + (size_t)b * SLEN;

    // ---- sequence length (mask is 1.0 for s < len, else 0.0) ----
    float msum = 0.f;
    for (int s = lane; s < SLEN; s += 64) msum += mask_b[s];
    msum = wave_sum(msum);
    const int len = (int)(msum + 0.5f);

    // ---- gold path score (partial; extras added by lane 0 at the end) ----
    // reference: trans_sc = transitions[tags[i], tags[i-1]]  (cur, prev)
    float g = 0.f;
    for (int i = lane; i < len; i += 64) {
        if (i >= 1) {
            const int tc = tags_b[i];
            const int tp = tags_b[i - 1];
            g += trans[tc * T + tp] + em_b[(size_t)i * T + tc];
        }
    }
    g = wave_sum(g);

    // ---- E column j in registers: E[k][j] = 2^(trans[k][j]*log2e) ----
    float Ecol[T];
    #pragma unroll
    for (int k = 0; k < T; ++k)
        Ecol[k] = exp2f(trans[k * T + j] * LOG2E);

    // ---- init: score0[j] = start[j] + em[b][0][j], convert to log2 domain ----
    const float z0 = (start_t[j] + em_b[j]) * LOG2E;
    const float m0 = wave_max(z0);                 // clones of col 47 don't hurt max
    float p = exp2f(z0 - m0);
    float L = m0;                                  // log2-domain accumulator

    // ---- forward scan with 4-deep emission prefetch ----
    const float* ep = em_b + j;                    // value for step s at ep[s*T]
    auto ld = [&](int s) -> float {
        const int ss = s < SLEN ? s : (SLEN - 1);  // clamp (value unused past len)
        return ep[(size_t)ss * T];
    };

    float f0 = ld(1), f1 = ld(2), f2 = ld(3), f3 = ld(4);

    auto do_step = [&](float& fv, int next_s) {
        float a0 = 0.f, a1 = 0.f, a2 = 0.f, a3 = 0.f;
        #pragma unroll
        for (int k = 0; k < T; k += 4) {
            a0 = fmaf(rlane(p, k + 0), Ecol[k + 0], a0);
            a1 = fmaf(rlane(p, k + 1), Ecol[k + 1], a1);
            a2 = fmaf(rlane(p, k + 2), Ecol[k + 2], a2);
            a3 = fmaf(rlane(p, k + 3), Ecol[k + 3], a3);
        }
        const float w = exp2f(fv * LOG2E);
        p = ((a0 + a1) + (a2 + a3)) * w;
        fv = ld(next_s);
    };

    int s = 1;
    while (s < len) {
        do_step(f0, s + 4); ++s; if (s >= len) break;
        do_step(f1, s + 4); ++s; if (s >= len) break;
        do_step(f2, s + 4); ++s; if (s >= len) break;
        do_step(f3, s + 4); ++s;
        // exact power-of-2 rescale every 4 steps
        const float mx = wave_max(p);
        const int   e  = ((__float_as_int(mx) >> 23) & 255) - 127;
        p *= __int_as_float((127 - e) << 23);      // * 2^(-e), exact
        L += (float)e;
    }

    // ---- finalize: fwd = ln( sum_j p[j] * exp(end[j]) ) + L*ln2 ----
    const float v  = (lane < T) ? p * exp2f(end_t[j] * LOG2E) : 0.f;
    const float S_ = wave_sum(v);
    const float fwd = (L + log2f(S_)) * LN2;

    if (lane == 0) {
        const int t0 = tags_b[0];
        const int tl = tags_b[len - 1];
        const float gold = g + start_t[t0] + em_b[t0] + end_t[tl];
        atomicAdd(out, (fwd - gold) * (1.0f / (float)BATCH));
    }
}

extern "C" void kernel_launch(void* const* d_in, const int* in_sizes, int n_in,
                              void* d_out, int out_size, void* d_ws, size_t ws_size,
                              hipStream_t stream) {
    const float* em      = (const float*)d_in[0];
    const int*   tags    = (const int*)  d_in[1];
    const float* mask    = (const float*)d_in[2];
    const float* trans   = (const float*)d_in[3];
    const float* start_t = (const float*)d_in[4];
    const float* end_t   = (const float*)d_in[5];
    float* out = (float*)d_out;

    hipMemsetAsync(out, 0, sizeof(float), stream);
    crf_kernel<<<BATCH, 64, 0, stream>>>(em, tags, mask, trans, start_t, end_t, out);
}

// Round 2
// 269.339 us; speedup vs baseline: 1.1358x; 1.1358x over previous
//
#include <hip/hip_runtime.h>

// CRF NLL: B=1024, S=512, T=48. One wave per batch element.
// Lane j holds forward state j (j<48); lanes 48..63 clone lane 47.
// Scaled linear-domain recursion:
//   p_{s+1}[j] = (sum_k p_s[k] * E[k][j]) * 2^(em[s][j]*log2e),  E = exp(trans)
// Exact power-of-2 rescale every 4 steps via readlane exponent probe
// (NOT a full wave_max -- keeps the LDS swizzle tree off the critical chain).
// Emission prefetch ring of 8 to cover ~900cyc HBM latency.

#define T 48
#define SLEN 512
#define BATCH 1024

__device__ __forceinline__ float wave_sum(float v) {
    #pragma unroll
    for (int m = 32; m >= 1; m >>= 1) v += __shfl_xor(v, m, 64);
    return v;
}

__device__ __forceinline__ float wave_max(float v) {
    #pragma unroll
    for (int m = 32; m >= 1; m >>= 1) v = fmaxf(v, __shfl_xor(v, m, 64));
    return v;
}

__device__ __forceinline__ float rlane(float v, int k) {
    return __int_as_float(__builtin_amdgcn_readlane(__float_as_int(v), k));
}

__global__ __launch_bounds__(64) void crf_kernel(
    const float* __restrict__ em,      // (B,S,T)
    const int*   __restrict__ tags,    // (B,S)
    const float* __restrict__ mask,    // (B,S)
    const float* __restrict__ trans,   // (T,T)  trans[cur*T+prev]; fwd uses [k][j]=k->j
    const float* __restrict__ start_t, // (T,)
    const float* __restrict__ end_t,   // (T,)
    float*       __restrict__ out)     // scalar
{
    constexpr float LOG2E = 1.4426950408889634f;
    constexpr float LN2   = 0.6931471805599453f;

    const int b    = blockIdx.x;
    const int lane = threadIdx.x;
    const int j    = lane < T ? lane : (T - 1);   // lanes 48..63 clone col 47

    const float* em_b   = em   + (size_t)b * SLEN * T;
    const float* mask_b = mask + (size_t)b * SLEN;
    const int*   tags_b = tags + (size_t)b * SLEN;

    // ---- sequence length ----
    float msum = 0.f;
    for (int s = lane; s < SLEN; s += 64) msum += mask_b[s];
    msum = wave_sum(msum);
    const int len = (int)(msum + 0.5f);

    // ---- gold path score (partial) ----
    float g = 0.f;
    for (int i = lane; i < len; i += 64) {
        if (i >= 1) {
            const int tc = tags_b[i];
            const int tp = tags_b[i - 1];
            g += trans[tc * T + tp] + em_b[(size_t)i * T + tc];
        }
    }
    g = wave_sum(g);

    // ---- E column j in registers ----
    float Ecol[T];
    #pragma unroll
    for (int k = 0; k < T; ++k)
        Ecol[k] = exp2f(trans[k * T + j] * LOG2E);

    // ---- init ----
    const float z0 = (start_t[j] + em_b[j]) * LOG2E;
    const float m0 = wave_max(z0);
    float p = exp2f(z0 - m0);
    float L = m0;

    // ---- emission prefetch ring (8 deep), clamped incremental offsets ----
    const float* ep = em_b + j;
    const int maxoff = (SLEN - 1) * T;
    int off = T;
    float f0, f1, f2, f3, f4, f5, f6, f7;
    f0 = ep[off < maxoff ? off : maxoff]; off += T;
    f1 = ep[off < maxoff ? off : maxoff]; off += T;
    f2 = ep[off < maxoff ? off : maxoff]; off += T;
    f3 = ep[off < maxoff ? off : maxoff]; off += T;
    f4 = ep[off < maxoff ? off : maxoff]; off += T;
    f5 = ep[off < maxoff ? off : maxoff]; off += T;
    f6 = ep[off < maxoff ? off : maxoff]; off += T;
    f7 = ep[off < maxoff ? off : maxoff]; off += T;

    auto stepf = [&](float& fv) {
        const float w = exp2f(fv * LOG2E);        // off critical chain (fv old)
        fv = ep[off < maxoff ? off : maxoff];     // refill: issue load early
        off += T;
        float a0 = 0.f, a1 = 0.f, a2 = 0.f, a3 = 0.f;
        #pragma unroll
        for (int k = 0; k < T; k += 4) {
            a0 = fmaf(rlane(p, k + 0), Ecol[k + 0], a0);
            a1 = fmaf(rlane(p, k + 1), Ecol[k + 1], a1);
            a2 = fmaf(rlane(p, k + 2), Ecol[k + 2], a2);
            a3 = fmaf(rlane(p, k + 3), Ecol[k + 3], a3);
        }
        p = ((a0 + a1) + (a2 + a3)) * w;
    };

    // Cheap exact rescale: sample 4 lanes' exponents (p>0 always). Clamp
    // e >= -64 so the scale factor stays finite even if sampled lanes
    // underflowed; ratio bound max(p)/sampled(p) <= 2^27 keeps us in range.
    auto rescale = [&]() {
        float m = fmaxf(fmaxf(rlane(p, 0), rlane(p, 16)),
                        fmaxf(rlane(p, 32), rlane(p, 47)));
        int e = ((__float_as_int(m) >> 23) & 255) - 127;
        e = e < -64 ? -64 : e;
        p *= __int_as_float((127 - e) << 23);     // * 2^(-e), exact
        L += (float)e;
    };

    int s = 1;
    while (s < len) {
        stepf(f0); if (++s >= len) break;
        stepf(f1); if (++s >= len) break;
        stepf(f2); if (++s >= len) break;
        stepf(f3); ++s; rescale(); if (s >= len) break;
        stepf(f4); if (++s >= len) break;
        stepf(f5); if (++s >= len) break;
        stepf(f6); if (++s >= len) break;
        stepf(f7); ++s; rescale();
    }

    // ---- finalize ----
    const float v  = (lane < T) ? p * exp2f(end_t[j] * LOG2E) : 0.f;
    const float S_ = wave_sum(v);
    const float fwd = (L + log2f(S_)) * LN2;

    if (lane == 0) {
        const int t0 = tags_b[0];
        const int tl = tags_b[len - 1];
        const float gold = g + start_t[t0] + em_b[t0] + end_t[tl];
        atomicAdd(out, (fwd - gold) * (1.0f / (float)BATCH));
    }
}

extern "C" void kernel_launch(void* const* d_in, const int* in_sizes, int n_in,
                              void* d_out, int out_size, void* d_ws, size_t ws_size,
                              hipStream_t stream) {
    const float* em      = (const float*)d_in[0];
    const int*   tags    = (const int*)  d_in[1];
    const float* mask    = (const float*)d_in[2];
    const float* trans   = (const float*)d_in[3];
    const float* start_t = (const float*)d_in[4];
    const float* end_t   = (const float*)d_in[5];
    float* out = (float*)d_out;

    hipMemsetAsync(out, 0, sizeof(float), stream);
    crf_kernel<<<BATCH, 64, 0, stream>>>(em, tags, mask, trans, start_t, end_t, out);
}

// Round 3
// 225.352 us; speedup vs baseline: 1.3575x; 1.1952x over previous
//
#include <hip/hip_runtime.h>

// CRF NLL: B=1024, S=512, T=48.
// Block = 128 threads = 2 waves per batch element:
//   wave 0: forward  p_s = p_{s-1} * M_s,  s = 1..mid          (lane j holds p[j], E-col j)
//   wave 1: backward u_{s-1} = M_s * u_s,  s = len-1..mid+1    (lane k holds u[k], E-row k)
// where M_s[k][j] = E[k][j] * w_s[j], E = exp(trans), w_s = exp(em_s).
// Combine: Z = 2^(Lf+Lb) * (p_mid . u_mid) via LDS.
// Halves serial depth (<=256 steps) AND gives 2 waves/SIMD so the HW
// scheduler hides readlane/FMA hazard stalls across waves.

#define T 48
#define SLEN 512
#define BATCH 1024

__device__ __forceinline__ float wave_sum(float v) {
    #pragma unroll
    for (int m = 32; m >= 1; m >>= 1) v += __shfl_xor(v, m, 64);
    return v;
}

__device__ __forceinline__ float wave_max(float v) {
    #pragma unroll
    for (int m = 32; m >= 1; m >>= 1) v = fmaxf(v, __shfl_xor(v, m, 64));
    return v;
}

__device__ __forceinline__ float rlane(float v, int k) {
    return __int_as_float(__builtin_amdgcn_readlane(__float_as_int(v), k));
}

__global__ __launch_bounds__(128) void crf_kernel(
    const float* __restrict__ em,      // (B,S,T)
    const int*   __restrict__ tags,    // (B,S)
    const float* __restrict__ mask,    // (B,S)
    const float* __restrict__ trans,   // (T,T): trans[prev*T+cur] in fwd sum
    const float* __restrict__ start_t, // (T,)
    const float* __restrict__ end_t,   // (T,)
    float*       __restrict__ out)     // scalar
{
    constexpr float LOG2E = 1.4426950408889634f;
    constexpr float LN2   = 0.6931471805599453f;

    const int b    = blockIdx.x;
    const int tid  = threadIdx.x;
    const int wave = tid >> 6;
    const int lane = tid & 63;
    const int j    = lane < T ? lane : (T - 1);   // clamped state index

    const float* em_b   = em   + (size_t)b * SLEN * T;
    const float* mask_b = mask + (size_t)b * SLEN;
    const int*   tags_b = tags + (size_t)b * SLEN;

    __shared__ float sP[T], sU[T];
    __shared__ float sLf, sLb, sGold;

    // ---- sequence length (each wave computes its own) ----
    float msum = 0.f;
    for (int s = lane; s < SLEN; s += 64) msum += mask_b[s];
    msum = wave_sum(msum);
    const int len = (int)(msum + 0.5f);
    const int mid = (len - 1) >> 1;                // fwd steps = mid, bwd = len-1-mid

    const float* ep = em_b + j;
    const int maxoff = (SLEN - 1) * T;

    // cheap exact power-of-2 rescale via 4-lane exponent probe
    auto rescale = [&](float& v, float& L) {
        float m = fmaxf(fmaxf(rlane(v, 0), rlane(v, 16)),
                        fmaxf(rlane(v, 32), rlane(v, 47)));
        int e = ((__float_as_int(m) >> 23) & 255) - 127;
        e = e < -64 ? -64 : e;
        v *= __int_as_float((127 - e) << 23);
        L += (float)e;
    };

    if (wave == 0) {
        // ================= FORWARD wave =================
        // gold path score (partial per-lane)
        float g = 0.f;
        for (int i = lane; i < len; i += 64) {
            if (i >= 1) {
                const int tc = tags_b[i];
                const int tp = tags_b[i - 1];
                g += trans[tc * T + tp] + em_b[(size_t)i * T + tc];
            }
        }
        g = wave_sum(g);

        float Ecol[T];                             // E[k][j] for my column j
        #pragma unroll
        for (int k = 0; k < T; ++k)
            Ecol[k] = exp2f(trans[k * T + j] * LOG2E);

        const float z0 = (start_t[j] + em_b[j]) * LOG2E;
        const float m0 = wave_max(z0);
        float p = exp2f(z0 - m0);
        float L = m0;

        // prefetch ring of 4 (ascending)
        int loff = T;
        auto ld = [&]() -> float {
            float v = ep[loff < maxoff ? loff : maxoff];
            loff += T;
            return v;
        };
        float f0 = ld(), f1 = ld(), f2 = ld(), f3 = ld();

        auto stepf = [&](float& fv) {
            const float w = exp2f(fv * LOG2E);
            fv = ld();
            float a0 = 0.f, a1 = 0.f, a2 = 0.f, a3 = 0.f;
            #pragma unroll
            for (int k = 0; k < T; k += 4) {
                a0 = fmaf(rlane(p, k + 0), Ecol[k + 0], a0);
                a1 = fmaf(rlane(p, k + 1), Ecol[k + 1], a1);
                a2 = fmaf(rlane(p, k + 2), Ecol[k + 2], a2);
                a3 = fmaf(rlane(p, k + 3), Ecol[k + 3], a3);
            }
            p = ((a0 + a1) + (a2 + a3)) * w;
        };

        int rem = mid;
        while (rem >= 4) {
            stepf(f0); stepf(f1); stepf(f2); stepf(f3);
            rescale(p, L);
            rem -= 4;
        }
        if (rem > 0) { stepf(f0); if (rem > 1) { stepf(f1); if (rem > 2) stepf(f2); } }
        rescale(p, L);

        if (lane < T) sP[lane] = p;
        if (lane == 0) {
            sLf = L;
            const int t0 = tags_b[0];
            const int tl = tags_b[len - 1];
            sGold = g + start_t[t0] + em_b[t0] + end_t[tl];
        }
    } else {
        // ================= BACKWARD wave =================
        float Erow[T];                             // E[k][jj] for my row k=j
        #pragma unroll
        for (int jj = 0; jj < T; ++jj)
            Erow[jj] = exp2f(trans[j * T + jj] * LOG2E);

        float u = exp2f(end_t[j] * LOG2E);         // u_{len-1}[k] = exp(end[k])
        float L = 0.f;

        // prefetch ring of 4 (descending from s = len-1)
        int loff = (len - 1) * T;
        auto ld = [&]() -> float {
            float v = ep[loff > 0 ? loff : 0];
            loff -= T;
            return v;
        };
        float f0 = ld(), f1 = ld(), f2 = ld(), f3 = ld();

        auto stepb = [&](float& fv) {
            const float t = u * exp2f(fv * LOG2E); // t[j] = w_s[j] * u_s[j]
            fv = ld();
            float a0 = 0.f, a1 = 0.f, a2 = 0.f, a3 = 0.f;
            #pragma unroll
            for (int k = 0; k < T; k += 4) {
                a0 = fmaf(rlane(t, k + 0), Erow[k + 0], a0);
                a1 = fmaf(rlane(t, k + 1), Erow[k + 1], a1);
                a2 = fmaf(rlane(t, k + 2), Erow[k + 2], a2);
                a3 = fmaf(rlane(t, k + 3), Erow[k + 3], a3);
            }
            u = ((a0 + a1) + (a2 + a3));
        };

        int rem = len - 1 - mid;                   // steps s = len-1 .. mid+1
        while (rem >= 4) {
            stepb(f0); stepb(f1); stepb(f2); stepb(f3);
            rescale(u, L);
            rem -= 4;
        }
        if (rem > 0) { stepb(f0); if (rem > 1) { stepb(f1); if (rem > 2) stepb(f2); } }
        rescale(u, L);

        if (lane < T) sU[lane] = u;
        if (lane == 0) sLb = L;
    }

    __syncthreads();

    // ---- combine (wave 0) ----
    if (wave == 0) {
        const float v  = (lane < T) ? sP[lane] * sU[lane] : 0.f;
        const float S_ = wave_sum(v);
        const float fwd = (sLf + sLb + log2f(S_)) * LN2;
        if (lane == 0)
            atomicAdd(out, (fwd - sGold) * (1.0f / (float)BATCH));
    }
}

extern "C" void kernel_launch(void* const* d_in, const int* in_sizes, int n_in,
                              void* d_out, int out_size, void* d_ws, size_t ws_size,
                              hipStream_t stream) {
    const float* em      = (const float*)d_in[0];
    const int*   tags    = (const int*)  d_in[1];
    const float* mask    = (const float*)d_in[2];
    const float* trans   = (const float*)d_in[3];
    const float* start_t = (const float*)d_in[4];
    const float* end_t   = (const float*)d_in[5];
    float* out = (float*)d_out;

    hipMemsetAsync(out, 0, sizeof(float), stream);
    crf_kernel<<<BATCH, 128, 0, stream>>>(em, tags, mask, trans, start_t, end_t, out);
}

// Round 4
// 216.649 us; speedup vs baseline: 1.4120x; 1.0402x over previous
//
#include <hip/hip_runtime.h>

// CRF NLL: B=1024, S=512, T=48. Block = 128 thr = 2 waves per batch:
//   wave 0: forward  half, wave 1: backward half (split at mid).
// Linear-domain recursion with exact pow2 rescale every 4 steps.
// Broadcast of the 48-vector per step via LDS same-address ds_read_b128
// (12 reads of float4, all lanes same addr = HW broadcast, no conflicts)
// instead of 48 v_readlane (quarter-rate / SGPR-hazard bound).

#define T 48
#define SLEN 512
#define BATCH 1024

__device__ __forceinline__ float wave_sum(float v) {
    #pragma unroll
    for (int m = 32; m >= 1; m >>= 1) v += __shfl_xor(v, m, 64);
    return v;
}
__device__ __forceinline__ float wave_max(float v) {
    #pragma unroll
    for (int m = 32; m >= 1; m >>= 1) v = fmaxf(v, __shfl_xor(v, m, 64));
    return v;
}
__device__ __forceinline__ float rlane(float v, int k) {
    return __int_as_float(__builtin_amdgcn_readlane(__float_as_int(v), k));
}

__global__ __launch_bounds__(128) void crf_kernel(
    const float* __restrict__ em,      // (B,S,T)
    const int*   __restrict__ tags,    // (B,S)
    const float* __restrict__ mask,    // (B,S)
    const float* __restrict__ trans,   // (T,T)
    const float* __restrict__ start_t, // (T,)
    const float* __restrict__ end_t,   // (T,)
    float*       __restrict__ out)     // scalar
{
    constexpr float LOG2E = 1.4426950408889634f;
    constexpr float LN2   = 0.6931471805599453f;

    const int b    = blockIdx.x;
    const int tid  = threadIdx.x;
    const int wave = tid >> 6;
    const int lane = tid & 63;
    const int j    = lane < T ? lane : (T - 1);   // clamped state index

    const float* em_b   = em   + (size_t)b * SLEN * T;
    const float* mask_b = mask + (size_t)b * SLEN;
    const int*   tags_b = tags + (size_t)b * SLEN;

    __shared__ float4 sbb[2][T / 4];              // per-wave broadcast buffer
    __shared__ float sP[T], sU[T];
    __shared__ float sLf, sLb, sGold;

    float*        sb  = (float*)&sbb[wave][0];
    const float4* sb4 = &sbb[wave][0];

    // ---- sequence length ----
    float msum = 0.f;
    for (int s = lane; s < SLEN; s += 64) msum += mask_b[s];
    msum = wave_sum(msum);
    const int len = (int)(msum + 0.5f);
    const int mid = (len - 1) >> 1;               // fwd steps = mid, bwd = len-1-mid

    const float* ep = em_b + j;
    const int maxoff = (SLEN - 1) * T;

    // exact power-of-2 rescale via 4-lane exponent probe (off inner chain)
    auto rescale = [&](float& v, float& L) {
        float m = fmaxf(fmaxf(rlane(v, 0), rlane(v, 16)),
                        fmaxf(rlane(v, 32), rlane(v, 47)));
        int e = ((__float_as_int(m) >> 23) & 255) - 127;
        e = e < -64 ? -64 : e;
        v *= __int_as_float((127 - e) << 23);
        L += (float)e;
    };

    if (wave == 0) {
        // ================= FORWARD wave =================
        float g = 0.f;
        for (int i = lane; i < len; i += 64) {
            if (i >= 1) {
                const int tc = tags_b[i];
                const int tp = tags_b[i - 1];
                g += trans[tc * T + tp] + em_b[(size_t)i * T + tc];
            }
        }
        g = wave_sum(g);

        float Ecol[T];                             // E[k][j] for my column j
        #pragma unroll
        for (int k = 0; k < T; ++k)
            Ecol[k] = exp2f(trans[k * T + j] * LOG2E);

        const float z0 = (start_t[j] + em_b[j]) * LOG2E;
        const float m0 = wave_max(z0);
        float p = exp2f(z0 - m0);
        float L = m0;

        int loff = T;
        auto ld = [&]() -> float {
            float v = ep[loff < maxoff ? loff : maxoff];
            loff += T;
            return v;
        };
        float f0 = ld(), f1 = ld(), f2 = ld(), f3 = ld();

        auto stepf = [&](float& fv) {
            const float w = exp2f(fv * LOG2E);     // off-chain (fv is old)
            fv = ld();
            sb[j] = p;                             // publish for broadcast
            float a0 = 0.f, a1 = 0.f, a2 = 0.f, a3 = 0.f;
            #pragma unroll
            for (int i = 0; i < T / 4; ++i) {
                const float4 q = sb4[i];           // same-addr = HW broadcast
                a0 = fmaf(q.x, Ecol[4 * i + 0], a0);
                a1 = fmaf(q.y, Ecol[4 * i + 1], a1);
                a2 = fmaf(q.z, Ecol[4 * i + 2], a2);
                a3 = fmaf(q.w, Ecol[4 * i + 3], a3);
            }
            p = ((a0 + a1) + (a2 + a3)) * w;
        };

        int rem = mid;
        while (rem >= 4) {
            stepf(f0); stepf(f1); stepf(f2); stepf(f3);
            rescale(p, L);
            rem -= 4;
        }
        if (rem > 0) { stepf(f0); if (rem > 1) { stepf(f1); if (rem > 2) stepf(f2); } }
        rescale(p, L);

        if (lane < T) sP[lane] = p;
        if (lane == 0) {
            sLf = L;
            const int t0 = tags_b[0];
            const int tl = tags_b[len - 1];
            sGold = g + start_t[t0] + em_b[t0] + end_t[tl];
        }
    } else {
        // ================= BACKWARD wave =================
        float Erow[T];                             // E[k=j][jj] row
        #pragma unroll
        for (int jj = 0; jj < T; ++jj)
            Erow[jj] = exp2f(trans[j * T + jj] * LOG2E);

        float u = exp2f(end_t[j] * LOG2E);
        float L = 0.f;

        int loff = (len - 1) * T;
        auto ld = [&]() -> float {
            float v = ep[loff > 0 ? loff : 0];
            loff -= T;
            return v;
        };
        float f0 = ld(), f1 = ld(), f2 = ld(), f3 = ld();

        auto stepb = [&](float& fv) {
            const float w = exp2f(fv * LOG2E);
            fv = ld();
            sb[j] = u * w;                         // publish t = u .* w_s
            float a0 = 0.f, a1 = 0.f, a2 = 0.f, a3 = 0.f;
            #pragma unroll
            for (int i = 0; i < T / 4; ++i) {
                const float4 q = sb4[i];
                a0 = fmaf(q.x, Erow[4 * i + 0], a0);
                a1 = fmaf(q.y, Erow[4 * i + 1], a1);
                a2 = fmaf(q.z, Erow[4 * i + 2], a2);
                a3 = fmaf(q.w, Erow[4 * i + 3], a3);
            }
            u = (a0 + a1) + (a2 + a3);
        };

        int rem = len - 1 - mid;
        while (rem >= 4) {
            stepb(f0); stepb(f1); stepb(f2); stepb(f3);
            rescale(u, L);
            rem -= 4;
        }
        if (rem > 0) { stepb(f0); if (rem > 1) { stepb(f1); if (rem > 2) stepb(f2); } }
        rescale(u, L);

        if (lane < T) sU[lane] = u;
        if (lane == 0) sLb = L;
    }

    __syncthreads();

    // ---- combine ----
    if (wave == 0) {
        const float v  = (lane < T) ? sP[lane] * sU[lane] : 0.f;
        const float S_ = wave_sum(v);
        const float fwd = (sLf + sLb + log2f(S_)) * LN2;
        if (lane == 0)
            atomicAdd(out, (fwd - sGold) * (1.0f / (float)BATCH));
    }
}

extern "C" void kernel_launch(void* const* d_in, const int* in_sizes, int n_in,
                              void* d_out, int out_size, void* d_ws, size_t ws_size,
                              hipStream_t stream) {
    const float* em      = (const float*)d_in[0];
    const int*   tags    = (const int*)  d_in[1];
    const float* mask    = (const float*)d_in[2];
    const float* trans   = (const float*)d_in[3];
    const float* start_t = (const float*)d_in[4];
    const float* end_t   = (const float*)d_in[5];
    float* out = (float*)d_out;

    hipMemsetAsync(out, 0, sizeof(float), stream);
    crf_kernel<<<BATCH, 128, 0, stream>>>(em, tags, mask, trans, start_t, end_t, out);
}

// Round 5
// 212.653 us; speedup vs baseline: 1.4386x; 1.0188x over previous
//
#include <hip/hip_runtime.h>

// CRF NLL: B=1024, S=512, T=48.  ONE wave per batch element (1024x64).
// The wave interleaves the forward chain (p, steps 1..nf) and the backward
// chain (u, steps len-1..nf+1); Z = 2^(Lf+Lb) * (p_nf . u_nf).
// Per iteration both chains do: 24 v_dot2_f32_f16 (packed E' in regs) fed by
// LDS same-address ds_read_b128 broadcasts of the f16-published state vector.
// Each chain's LDS write->read round-trip overlaps the OTHER chain's compute,
// taking the RT latency off the serial chain (the R4 bottleneck).
// E' = exp(trans) * 2^-8 folded scale keeps f16-published values in range;
// exact pow2 probe-rescale every 4 iters; publish clamped at 60000.

#define T 48
#define SLEN 512
#define BATCH 1024

typedef _Float16 h2 __attribute__((ext_vector_type(2)));
typedef _Float16 h8v __attribute__((ext_vector_type(8)));
typedef h8v h8 __attribute__((may_alias));
typedef _Float16 f16ma __attribute__((may_alias));

__device__ __forceinline__ float wave_sum(float v) {
    #pragma unroll
    for (int m = 32; m >= 1; m >>= 1) v += __shfl_xor(v, m, 64);
    return v;
}
__device__ __forceinline__ float wave_max(float v) {
    #pragma unroll
    for (int m = 32; m >= 1; m >>= 1) v = fmaxf(v, __shfl_xor(v, m, 64));
    return v;
}
__device__ __forceinline__ float rlane(float v, int k) {
    return __int_as_float(__builtin_amdgcn_readlane(__float_as_int(v), k));
}
__device__ __forceinline__ float fdot2(h2 a, h2 b, float c) {
#if __has_builtin(__builtin_amdgcn_fdot2)
    return __builtin_amdgcn_fdot2(a, b, c, false);
#else
    return fmaf((float)a[1], (float)b[1], fmaf((float)a[0], (float)b[0], c));
#endif
}

#define H2OF(q, i) (__builtin_shufflevector((q), (q), 2*(i), 2*(i)+1))
#define DOTG(q, E, base, A0, A1, A2, A3)        \
    A0 = fdot2(H2OF(q,0), E[(base)+0], A0);     \
    A1 = fdot2(H2OF(q,1), E[(base)+1], A1);     \
    A2 = fdot2(H2OF(q,2), E[(base)+2], A2);     \
    A3 = fdot2(H2OF(q,3), E[(base)+3], A3);
#define DOT48(E, A0, A1, A2, A3, Q0,Q1,Q2,Q3,Q4,Q5) \
    DOTG(Q0, E, 0,  A0,A1,A2,A3)                \
    DOTG(Q1, E, 4,  A0,A1,A2,A3)                \
    DOTG(Q2, E, 8,  A0,A1,A2,A3)                \
    DOTG(Q3, E, 12, A0,A1,A2,A3)                \
    DOTG(Q4, E, 16, A0,A1,A2,A3)                \
    DOTG(Q5, E, 20, A0,A1,A2,A3)

__global__ __launch_bounds__(64) void crf_kernel(
    const float* __restrict__ em,      // (B,S,T)
    const int*   __restrict__ tags,    // (B,S)
    const float* __restrict__ mask,    // (B,S)
    const float* __restrict__ trans,   // (T,T)
    const float* __restrict__ start_t, // (T,)
    const float* __restrict__ end_t,   // (T,)
    float*       __restrict__ out)     // scalar
{
    constexpr float LOG2E = 1.4426950408889634f;
    constexpr float LN2   = 0.6931471805599453f;
    constexpr float ESC   = -8.0f;     // fold 2^-8 into E' for f16 range

    const int b    = blockIdx.x;
    const int lane = threadIdx.x;
    const int j    = lane < T ? lane : (T - 1);

    const float* em_b   = em   + (size_t)b * SLEN * T;
    const float* mask_b = mask + (size_t)b * SLEN;
    const int*   tags_b = tags + (size_t)b * SLEN;

    __shared__ __align__(16) _Float16 bufF[64];
    __shared__ __align__(16) _Float16 bufB[64];
    f16ma* wF = (f16ma*)bufF;
    f16ma* wB = (f16ma*)bufB;
    const h8* F8 = (const h8*)bufF;
    const h8* B8 = (const h8*)bufB;

    // ---- sequence length ----
    float msum = 0.f;
    for (int s = lane; s < SLEN; s += 64) msum += mask_b[s];
    msum = wave_sum(msum);
    const int len = (int)(msum + 0.5f);
    const int nb  = (len - 1) >> 1;           // bwd steps (joint iters)
    const int nf  = (len - 1) - nb;           // fwd steps = nb or nb+1

    // ---- gold path score ----
    float g = 0.f;
    for (int i = lane; i < len; i += 64) {
        if (i >= 1) {
            const int tc = tags_b[i];
            const int tp = tags_b[i - 1];
            g += trans[tc * T + tp] + em_b[(size_t)i * T + tc];
        }
    }
    g = wave_sum(g);

    // ---- packed E' fragments: col j (fwd) and row j (bwd), pairs over k ----
    h2 Ec[24], Er[24];
    #pragma unroll
    for (int k = 0; k < T; k += 2) {
        h2 c, r;
        c[0] = (_Float16)exp2f(trans[(k    ) * T + j] * LOG2E + ESC);
        c[1] = (_Float16)exp2f(trans[(k + 1) * T + j] * LOG2E + ESC);
        r[0] = (_Float16)exp2f(trans[j * T + (k    )] * LOG2E + ESC);
        r[1] = (_Float16)exp2f(trans[j * T + (k + 1)] * LOG2E + ESC);
        Ec[k >> 1] = c; Er[k >> 1] = r;
    }

    // ---- init ----
    const float z0 = (start_t[j] + em_b[j]) * LOG2E;
    const float m0 = wave_max(z0);
    float pf = exp2f(z0 - m0);
    float u  = exp2f(end_t[j] * LOG2E);
    float Lf = m0, Lb = 0.f;

    const float* ep = em_b + j;
    const int maxoff = (SLEN - 1) * T;

    // emissions needed at known one-off positions (prefetch now)
    const float vlast  = ep[(size_t)(len - 1) * T];   // bwd init weight
    const float vextra = ep[(size_t)nf * T];          // extra fwd step weight

    // publish initial vectors, issue initial broadcast reads
    wF[lane] = (_Float16)pf;
    wB[lane] = (_Float16)fminf(u * exp2f(vlast * LOG2E), 60000.f);
    h8 qF0=F8[0],qF1=F8[1],qF2=F8[2],qF3=F8[3],qF4=F8[4],qF5=F8[5];
    h8 qB0=B8[0],qB1=B8[1],qB2=B8[2],qB3=B8[3],qB4=B8[4],qB5=B8[5];

    // emission rings (4 deep each)
    int fo = T;
    float f0 = ep[fo < maxoff ? fo : maxoff]; fo += T;
    float f1 = ep[fo < maxoff ? fo : maxoff]; fo += T;
    float f2 = ep[fo < maxoff ? fo : maxoff]; fo += T;
    float f3 = ep[fo < maxoff ? fo : maxoff]; fo += T;
    int bo = (len - 2) * T;
    float e0 = ep[bo > 0 ? bo : 0]; bo -= T;
    float e1 = ep[bo > 0 ? bo : 0]; bo -= T;
    float e2 = ep[bo > 0 ? bo : 0]; bo -= T;
    float e3 = ep[bo > 0 ? bo : 0]; bo -= T;

    auto rescale = [&](float& v, float& L) {   // exact pow2, 4-lane probe
        float m = fmaxf(fmaxf(rlane(v, 0), rlane(v, 16)),
                        fmaxf(rlane(v, 32), rlane(v, 47)));
        int e = ((__float_as_int(m) >> 23) & 255) - 127;
        e = e < -64 ? -64 : e;
        v *= __int_as_float((127 - e) << 23);
        L += (float)e;
    };

    auto jiter = [&](float& fe, float& be, bool resc) {
        // ---- forward half: consume qF (issued last iter), publish, re-read
        float wf = exp2f(fe * LOG2E);
        fe = ep[fo < maxoff ? fo : maxoff]; fo += T;
        float a0=0.f, a1=0.f, a2=0.f, a3=0.f;
        DOT48(Ec, a0,a1,a2,a3, qF0,qF1,qF2,qF3,qF4,qF5)
        float pn = ((a0 + a1) + (a2 + a3)) * wf;
        if (resc) rescale(pn, Lf);
        pf = pn;
        wF[lane] = (_Float16)fminf(pn, 60000.f);
        qF0=F8[0];qF1=F8[1];qF2=F8[2];qF3=F8[3];qF4=F8[4];qF5=F8[5];
        // ---- backward half
        float wb = exp2f(be * LOG2E);
        be = ep[bo > 0 ? bo : 0]; bo -= T;
        float c0=0.f, c1=0.f, c2=0.f, c3=0.f;
        DOT48(Er, c0,c1,c2,c3, qB0,qB1,qB2,qB3,qB4,qB5)
        float un = (c0 + c1) + (c2 + c3);
        if (resc) rescale(un, Lb);
        u = un;
        wB[lane] = (_Float16)fminf(un * wb, 60000.f);
        qB0=B8[0];qB1=B8[1];qB2=B8[2];qB3=B8[3];qB4=B8[4];qB5=B8[5];
    };

    int rem = nb;
    while (rem >= 4) {
        jiter(f0, e0, false);
        jiter(f1, e1, false);
        jiter(f2, e2, false);
        jiter(f3, e3, true);
        rem -= 4;
    }
    if (rem > 0) { jiter(f0, e0, false);
        if (rem > 1) { jiter(f1, e1, false);
            if (rem > 2) jiter(f2, e2, false); } }

    // ---- extra forward step (nf = nb+1 case); qF holds p_nb broadcast ----
    if (nf > nb) {
        float wf = exp2f(vextra * LOG2E);
        float a0=0.f, a1=0.f, a2=0.f, a3=0.f;
        DOT48(Ec, a0,a1,a2,a3, qF0,qF1,qF2,qF3,qF4,qF5)
        pf = ((a0 + a1) + (a2 + a3)) * wf;
    }

    // ---- finalize: undo folded 2^-8 per step, combine at m = nf ----
    Lf += 8.0f * (float)nf;
    Lb += 8.0f * (float)nb;
    const float v  = (lane < T) ? pf * u : 0.f;
    const float S_ = wave_sum(v);
    const float fwd = (Lf + Lb + log2f(S_)) * LN2;

    if (lane == 0) {
        const int t0 = tags_b[0];
        const int tl = tags_b[len - 1];
        const float gold = g + start_t[t0] + em_b[t0] + end_t[tl];
        atomicAdd(out, (fwd - gold) * (1.0f / (float)BATCH));
    }
}

extern "C" void kernel_launch(void* const* d_in, const int* in_sizes, int n_in,
                              void* d_out, int out_size, void* d_ws, size_t ws_size,
                              hipStream_t stream) {
    const float* em      = (const float*)d_in[0];
    const int*   tags    = (const int*)  d_in[1];
    const float* mask    = (const float*)d_in[2];
    const float* trans   = (const float*)d_in[3];
    const float* start_t = (const float*)d_in[4];
    const float* end_t   = (const float*)d_in[5];
    float* out = (float*)d_out;

    hipMemsetAsync(out, 0, sizeof(float), stream);
    crf_kernel<<<BATCH, 64, 0, stream>>>(em, tags, mask, trans, start_t, end_t, out);
}